// Round 2
// baseline (541.814 us; speedup 1.0000x reference)
//
#include <hip/hip_runtime.h>

#define D 128
#define KNBR 32
#define BATCH 8192
#define NCLASS 60

// ---------------------------------------------------------------------------
// K0: prep. blk0: wqa = Wq@a[:D], wka = Wk@a[D:]   (LDS-staged, transposed read)
//          blk1: be = We_b @ Wuc[384:512]
//          blks 2..49: Wcomb2 = [Wk@Wuc[128:256]; Wk@Wuc[256:384]; We_w@Wuc[384:512]]
//                      (3 gemms x 16 row-blocks of 8 rows)
__global__ __launch_bounds__(256) void k_prep(
    const float* __restrict__ Wq, const float* __restrict__ Wk,
    const float* __restrict__ a, const float* __restrict__ Wew,
    const float* __restrict__ Web, const float* __restrict__ Wuc,
    float* __restrict__ wqa, float* __restrict__ wka,
    float* __restrict__ be, float* __restrict__ Wcomb2)
{
    __shared__ float sB[128][129];
    int blk = blockIdx.x, tid = threadIdx.x;
    if (blk == 0) {
        // stage Wq, compute wqa; then Wk, wka
        for (int t = tid; t < 128 * 128; t += 256) sB[t >> 7][t & 127] = Wq[t];
        __syncthreads();
        if (tid < 128) {
            float s = 0.f;
            for (int j = 0; j < D; ++j) s += sB[tid][j] * a[j];
            wqa[tid] = s;
        }
        __syncthreads();
        for (int t = tid; t < 128 * 128; t += 256) sB[t >> 7][t & 127] = Wk[t];
        __syncthreads();
        if (tid < 128) {
            float s = 0.f;
            for (int j = 0; j < D; ++j) s += sB[tid][j] * a[D + j];
            wka[tid] = s;
        }
    } else if (blk == 1) {
        if (tid < 128) {
            float acc = 0.f;
            for (int j = 0; j < D; ++j) acc += Web[j] * Wuc[(size_t)(384 + j) * D + tid];
            be[tid] = acc;
        }
    } else {
        int g  = (blk - 2) >> 4;          // which gemm: 0,1 -> Wk, 2 -> Wew
        int rb = ((blk - 2) & 15) * 8;    // row base (8 rows per block)
        const float* A = (g == 2) ? Wew : Wk;
        const float* B = Wuc + (size_t)(128 + g * 128) * D;
        for (int t = tid; t < 128 * 128; t += 256) sB[t >> 7][t & 127] = B[t];
        __syncthreads();
        int j = tid & 127, half = tid >> 7;
        float acc[4] = {0.f, 0.f, 0.f, 0.f};
        int r0 = rb + half * 4;
        for (int t = 0; t < 128; ++t) {
            float bv = sB[t][j];
            #pragma unroll
            for (int m = 0; m < 4; ++m)
                acc[m] = fmaf(A[(size_t)(r0 + m) * D + t], bv, acc[m]);
        }
        #pragma unroll
        for (int m = 0; m < 4; ++m)
            Wcomb2[(size_t)(g * 128 + r0 + m) * D + j] = acc[m];
    }
}

// ---------------------------------------------------------------------------
// K1: attention -> nbsum only (Wk matvec folded into Wcomb2).
__global__ __launch_bounds__(256) void k_attend(
    const float* __restrict__ mem,
    const float* __restrict__ wqa, const float* __restrict__ wka,
    const int* __restrict__ src_idxs, const int* __restrict__ dst_idxs,
    const int* __restrict__ src_nb, const int* __restrict__ dst_nb,
    float* __restrict__ nbsumbuf)
{
    int b = blockIdx.x, side = blockIdx.y, tid = threadIdx.x;
    const int* idxs = side ? dst_idxs : src_idxs;
    const int* nbrs = side ? dst_nb  : src_nb;

    __shared__ int   s_idx[KNBR];
    __shared__ float s_nb[KNBR][D];
    __shared__ float s_sk[KNBR];
    __shared__ float s_attn[KNBR];
    __shared__ float s_sq;
    __shared__ float s_part[2][D];

    if (tid < KNBR) s_idx[tid] = nbrs[b * KNBR + tid];
    if (tid < 32) {
        // self row + sq = self . wqa
        int node = idxs[b];
        float4 self4 = ((const float4*)(mem + (size_t)node * D))[tid];
        float4 wq4   = ((const float4*)wqa)[tid];
        float p = self4.x * wq4.x + self4.y * wq4.y + self4.z * wq4.z + self4.w * wq4.w;
        #pragma unroll
        for (int m = 1; m <= 16; m <<= 1) p += __shfl_xor(p, m, 32);
        if (tid == 0) s_sq = p;
    }
    __syncthreads();

    // gather 32 neighbor rows + sk partials on the fly
    int c4 = tid & 31;
    int rbase = tid >> 5;          // 0..7
    float4 wk4 = ((const float4*)wka)[c4];
    #pragma unroll
    for (int p = 0; p < 4; ++p) {
        int r = rbase + 8 * p;
        float4 v = ((const float4*)(mem + (size_t)s_idx[r] * D))[c4];
        *(float4*)&s_nb[r][c4 * 4] = v;
        float pr = v.x * wk4.x + v.y * wk4.y + v.z * wk4.z + v.w * wk4.w;
        #pragma unroll
        for (int m = 1; m <= 16; m <<= 1) pr += __shfl_xor(pr, m, 32);
        if (c4 == 0) s_sk[r] = pr;
    }
    __syncthreads();

    // softmax over 32 scores, parallel on one 32-lane group
    if (tid < 32) {
        float x = s_sq + s_sk[tid];
        x = (x >= 0.f) ? x : 0.2f * x;      // leaky_relu(0.2)
        float mx = x;
        #pragma unroll
        for (int m = 1; m <= 16; m <<= 1) mx = fmaxf(mx, __shfl_xor(mx, m, 32));
        float e = __expf(x - mx);
        float sum = e;
        #pragma unroll
        for (int m = 1; m <= 16; m <<= 1) sum += __shfl_xor(sum, m, 32);
        s_attn[tid] = e / sum;
    }
    __syncthreads();

    // weighted neighbor sum
    int col = tid & 127, half = tid >> 7;
    float acc = 0.f;
    int k0 = half * 16;
    #pragma unroll
    for (int k = 0; k < 16; ++k) acc = fmaf(s_attn[k0 + k], s_nb[k0 + k][col], acc);
    s_part[half][col] = acc;
    __syncthreads();
    if (tid < 128)
        nbsumbuf[((size_t)side * BATCH + b) * D + tid] = s_part[0][tid] + s_part[1][tid];
}

// ---------------------------------------------------------------------------
// K2: msg = relu([self | nbsum_s | nbsum_o | ef] @ Wcomb + be)
// Tiled GEMM: Mtile=64, N=128, K=512 (16 k-tiles of 32). 4x8 micro per thread.
__global__ __launch_bounds__(256) void k_msg(
    const float* __restrict__ mem, const float* __restrict__ edge_feat,
    const float* __restrict__ Wuc, const float* __restrict__ Wcomb2,
    const float* __restrict__ be,
    const int* __restrict__ src_idxs, const int* __restrict__ dst_idxs,
    const int* __restrict__ edge_idxs,
    const float* __restrict__ nbsumbuf, float* __restrict__ msgbuf)
{
    int side = blockIdx.y;
    int b0 = blockIdx.x * 64;
    int tid = threadIdx.x;

    __shared__ float Ast[32][68];    // A-tile transposed [k][row], padded
    __shared__ float Ws[32][128];    // W-tile [k][col]
    __shared__ int s_bidx[64], s_eidx[64];

    if (tid < 64) {
        s_bidx[tid] = (side ? dst_idxs : src_idxs)[b0 + tid];
        s_eidx[tid] = edge_idxs[b0 + tid];
    }
    __syncthreads();

    int tr = tid >> 4, tc = tid & 15;         // 16x16 thread grid
    int lc = tid & 31, lr = tid >> 5;         // A-load lane
    int wc = tid & 127, wk2 = tid >> 7;       // W-load lane
    float acc[4][8];
    #pragma unroll
    for (int i = 0; i < 4; ++i)
        #pragma unroll
        for (int j = 0; j < 8; ++j) acc[i][j] = 0.f;

    for (int kt = 0; kt < 16; ++kt) {
        int seg = kt >> 2, off = (kt & 3) * 32;
        if (seg == 0) {
            #pragma unroll
            for (int p = 0; p < 8; ++p) {
                int r = lr + 8 * p;
                Ast[lc][r] = mem[(size_t)s_bidx[r] * D + off + lc];
            }
        } else if (seg == 1) {
            #pragma unroll
            for (int p = 0; p < 8; ++p) {
                int r = lr + 8 * p;
                Ast[lc][r] = nbsumbuf[((size_t)side * BATCH + b0 + r) * D + off + lc];
            }
        } else if (seg == 2) {
            #pragma unroll
            for (int p = 0; p < 8; ++p) {
                int r = lr + 8 * p;
                Ast[lc][r] = nbsumbuf[((size_t)(1 - side) * BATCH + b0 + r) * D + off + lc];
            }
        } else {
            #pragma unroll
            for (int p = 0; p < 8; ++p) {
                int r = lr + 8 * p;
                Ast[lc][r] = edge_feat[(size_t)s_eidx[r] * D + off + lc];
            }
        }
        int krow0 = kt * 32;
        #pragma unroll
        for (int p = 0; p < 16; ++p) {
            int kk = wk2 + 2 * p;
            int gr = krow0 + kk;
            Ws[kk][wc] = (gr < 128) ? Wuc[(size_t)gr * D + wc]
                                    : Wcomb2[(size_t)(gr - 128) * D + wc];
        }
        __syncthreads();
        #pragma unroll 4
        for (int kk = 0; kk < 32; ++kk) {
            float4 a4 = *(const float4*)&Ast[kk][tr * 4];
            float4 w0 = *(const float4*)&Ws[kk][tc * 4];
            float4 w1 = *(const float4*)&Ws[kk][64 + tc * 4];
            float ar[4] = {a4.x, a4.y, a4.z, a4.w};
            float wr[8] = {w0.x, w0.y, w0.z, w0.w, w1.x, w1.y, w1.z, w1.w};
            #pragma unroll
            for (int i = 0; i < 4; ++i)
                #pragma unroll
                for (int j = 0; j < 8; ++j)
                    acc[i][j] = fmaf(ar[i], wr[j], acc[i][j]);
        }
        __syncthreads();
    }

    float4 bv0 = *(const float4*)&be[tc * 4];
    float4 bv1 = *(const float4*)&be[64 + tc * 4];
    #pragma unroll
    for (int i = 0; i < 4; ++i) {
        size_t row = (size_t)side * BATCH + b0 + tr * 4 + i;
        float4 o0 = make_float4(fmaxf(acc[i][0] + bv0.x, 0.f), fmaxf(acc[i][1] + bv0.y, 0.f),
                                fmaxf(acc[i][2] + bv0.z, 0.f), fmaxf(acc[i][3] + bv0.w, 0.f));
        float4 o1 = make_float4(fmaxf(acc[i][4] + bv1.x, 0.f), fmaxf(acc[i][5] + bv1.y, 0.f),
                                fmaxf(acc[i][6] + bv1.z, 0.f), fmaxf(acc[i][7] + bv1.w, 0.f));
        *(float4*)&msgbuf[row * D + tc * 4] = o0;
        *(float4*)&msgbuf[row * D + 64 + tc * 4] = o1;
    }
}

// ---------------------------------------------------------------------------
// K3: logits = relu(msg @ Wc1) @ Wc2.  Mtile=32: GEMM1 (2x8 micro) -> relu ->
// HsT (transposed in LDS) -> GEMM2 vs LDS-staged Wc2.
__global__ __launch_bounds__(256) void k_cls(
    const float* __restrict__ msgbuf, const float* __restrict__ Wc1,
    const float* __restrict__ Wc2, float* __restrict__ out)
{
    int side = blockIdx.y;
    int b0 = blockIdx.x * 32;
    int tid = threadIdx.x;

    __shared__ float Ast[32][36];     // [k][row]
    __shared__ float Ws[32][128];     // Wc1 k-tile
    __shared__ float HsT[128][36];    // h1 transposed [col(k2)][row]
    __shared__ float Wc2s[128][64];   // padded cols 60..63 unused

    for (int t = tid; t < 128 * 60; t += 256) {
        int kk = t / 60, c = t - kk * 60;
        Wc2s[kk][c] = Wc2[t];
    }

    int tr = tid >> 4, tc = tid & 15;
    int lc = tid & 31, lr = tid >> 5;
    int wc = tid & 127, wk2 = tid >> 7;
    float acc[2][8];
    #pragma unroll
    for (int i = 0; i < 2; ++i)
        #pragma unroll
        for (int j = 0; j < 8; ++j) acc[i][j] = 0.f;

    for (int kt = 0; kt < 4; ++kt) {
        int off = kt * 32;
        #pragma unroll
        for (int p = 0; p < 4; ++p) {
            int r = lr + 8 * p;
            Ast[lc][r] = msgbuf[((size_t)side * BATCH + b0 + r) * D + off + lc];
        }
        #pragma unroll
        for (int p = 0; p < 16; ++p) {
            int kk = wk2 + 2 * p;
            Ws[kk][wc] = Wc1[(size_t)(off + kk) * D + wc];
        }
        __syncthreads();
        #pragma unroll 4
        for (int kk = 0; kk < 32; ++kk) {
            float2 a2 = *(const float2*)&Ast[kk][tr * 2];
            float4 w0 = *(const float4*)&Ws[kk][tc * 4];
            float4 w1 = *(const float4*)&Ws[kk][64 + tc * 4];
            float ar[2] = {a2.x, a2.y};
            float wr[8] = {w0.x, w0.y, w0.z, w0.w, w1.x, w1.y, w1.z, w1.w};
            #pragma unroll
            for (int i = 0; i < 2; ++i)
                #pragma unroll
                for (int j = 0; j < 8; ++j)
                    acc[i][j] = fmaf(ar[i], wr[j], acc[i][j]);
        }
        __syncthreads();
    }

    // relu -> HsT[col][row]
    #pragma unroll
    for (int i = 0; i < 2; ++i) {
        int r = tr * 2 + i;
        #pragma unroll
        for (int j = 0; j < 4; ++j) {
            HsT[tc * 4 + j][r]      = fmaxf(acc[i][j], 0.f);
            HsT[64 + tc * 4 + j][r] = fmaxf(acc[i][j + 4], 0.f);
        }
    }
    __syncthreads();

    // GEMM2: [32 x 128] @ [128 x 60]
    int r0 = (tid >> 4) * 2;
    int cg = tid & 15;
    int c0 = cg * 4;
    float acc2[2][4];
    #pragma unroll
    for (int i = 0; i < 2; ++i)
        #pragma unroll
        for (int j = 0; j < 4; ++j) acc2[i][j] = 0.f;
    for (int kk = 0; kk < 128; ++kk) {
        float2 h2 = *(const float2*)&HsT[kk][r0];
        float4 w4 = *(const float4*)&Wc2s[kk][c0];
        float wr[4] = {w4.x, w4.y, w4.z, w4.w};
        #pragma unroll
        for (int j = 0; j < 4; ++j) {
            acc2[0][j] = fmaf(h2.x, wr[j], acc2[0][j]);
            acc2[1][j] = fmaf(h2.y, wr[j], acc2[1][j]);
        }
    }
    if (cg < 15) {
        #pragma unroll
        for (int i = 0; i < 2; ++i) {
            size_t row = (size_t)side * BATCH + b0 + r0 + i;
            *(float4*)&out[row * NCLASS + c0] =
                make_float4(acc2[i][0], acc2[i][1], acc2[i][2], acc2[i][3]);
        }
    }
}

// ---------------------------------------------------------------------------
extern "C" void kernel_launch(void* const* d_in, const int* in_sizes, int n_in,
                              void* d_out, int out_size, void* d_ws, size_t ws_size,
                              hipStream_t stream) {
    const float* mem       = (const float*)d_in[0];
    const float* edge_feat = (const float*)d_in[1];
    const float* Wq        = (const float*)d_in[2];
    const float* Wk        = (const float*)d_in[3];
    const float* a         = (const float*)d_in[4];
    const float* Wew       = (const float*)d_in[5];
    const float* Web       = (const float*)d_in[6];
    const float* Wuc       = (const float*)d_in[7];
    const float* Wc1       = (const float*)d_in[8];
    const float* Wc2       = (const float*)d_in[9];
    const int* src_idxs    = (const int*)d_in[10];
    const int* dst_idxs    = (const int*)d_in[11];
    const int* edge_idxs   = (const int*)d_in[12];
    const int* src_nb      = (const int*)d_in[13];
    const int* dst_nb      = (const int*)d_in[14];
    float* out = (float*)d_out;

    float* ws = (float*)d_ws;
    float* Wcomb2 = ws;                  // 384*128 = 49152
    float* be     = ws + 49152;          // 128
    float* wqa    = ws + 49280;          // 128
    float* wka    = ws + 49408;          // 128
    float* nbsum  = ws + 49536;          // 2*8192*128 = 2097152
    float* msgbuf = nbsum + 2097152;     // 2*8192*128

    k_prep<<<50, 256, 0, stream>>>(Wq, Wk, a, Wew, Web, Wuc, wqa, wka, be, Wcomb2);
    k_attend<<<dim3(BATCH, 2), 256, 0, stream>>>(mem, wqa, wka,
                                                 src_idxs, dst_idxs, src_nb, dst_nb,
                                                 nbsum);
    k_msg<<<dim3(BATCH / 64, 2), 256, 0, stream>>>(mem, edge_feat, Wuc, Wcomb2, be,
                                                   src_idxs, dst_idxs, edge_idxs,
                                                   nbsum, msgbuf);
    k_cls<<<dim3(BATCH / 32, 2), 256, 0, stream>>>(msgbuf, Wc1, Wc2, out);
}